// Round 4
// baseline (186.834 us; speedup 1.0000x reference)
//
#include <hip/hip_runtime.h>
#include <hip/hip_bf16.h>

#define Bb 8
#define Nn 1024
#define Hh 12
#define C3 2304
#define KK_E 0.1803368801f   // (1/8) * log2(e)
#define NQB 128              // queries per block (4 waves x 32)
#define KVBLK 64
#define NT 29
#define NQT (Nn / NQB)       // 8
#define NKT (Nn / KVBLK)     // 16
#define NBLK (Bb * Hh * NQT) // 768
#define TILE_ELEMS 4096      // 64x64 bf16 tile

typedef short bf16x8 __attribute__((ext_vector_type(8)));
typedef float f32x4 __attribute__((ext_vector_type(4)));
typedef unsigned short u16t;

__device__ __forceinline__ float b2f(u16t v) {
    union { unsigned u; float f; } x; x.u = ((unsigned)v) << 16; return x.f;
}
__device__ __forceinline__ u16t f2b(float f) {
    union { float f; unsigned u; } x; x.f = f;
    unsigned r = x.u + 0x7fffu + ((x.u >> 16) & 1u);
    return (u16t)(r >> 16);
}
__device__ __forceinline__ unsigned pk2(float a, float b) {
    union { __hip_bfloat162 h; unsigned u; } cv;
    cv.h = __float22bfloat162_rn(make_float2(a, b));
    return cv.u;
}
// swizzled element index for row-major [rows][64] bf16 LDS tiles (128B rows)
__device__ __forceinline__ int swz(int row, int col) {
    return (row * 64 + col) ^ ((row & 7) << 3);
}

// ---------------- pass 1: fp32 -> bf16; K tiles row-major [key][d], V tiles transposed [d][key]
__global__ __launch_bounds__(256) void preconv_kernel(
        const float* __restrict__ x, u16t* __restrict__ wsK, u16t* __restrict__ wsV) {
    __shared__ __align__(16) u16t Vt[TILE_ELEMS];
    const int bid = blockIdx.x;                 // ((b*H + h)*NKT + kt)
    const int kt = bid % NKT;
    const int h  = (bid / NKT) % Hh;
    const int b  = bid / (NKT * Hh);
    const int tid = threadIdx.x;
    const float* xb = x + (size_t)b * Nn * C3 + (size_t)kt * KVBLK * C3 + 768 + h * 64;
    u16t* Kdst = wsK + (size_t)bid * TILE_ELEMS;
    u16t* Vdst = wsV + (size_t)bid * TILE_ELEMS;

    #pragma unroll
    for (int rep = 0; rep < 4; ++rep) {
        int idx = tid + rep * 256;
        int m = idx >> 4;               // key row
        int d0 = (idx & 15) * 4;
        const float* src = &xb[(size_t)m * C3 + d0];
        float4 k4 = *(const float4*)src;
        ushort4 s4;
        s4.x = f2b(k4.x); s4.y = f2b(k4.y); s4.z = f2b(k4.z); s4.w = f2b(k4.w);
        *(ushort4*)&Kdst[m * 64 + d0] = s4;         // linear row-major
        float4 v4 = *(const float4*)(src + 768);
        Vt[swz(d0 + 0, m)] = f2b(v4.x);             // swizzled transposed bounce
        Vt[swz(d0 + 1, m)] = f2b(v4.y);
        Vt[swz(d0 + 2, m)] = f2b(v4.z);
        Vt[swz(d0 + 3, m)] = f2b(v4.w);
    }
    __syncthreads();
    // unswizzling copy-out: 512 chunks of 16B; chunk i holds rows i>>3, slot (i&7)^((i>>3)&7)
    #pragma unroll
    for (int i = tid; i < 512; i += 256) {
        int sc = (i & ~7) | ((i & 7) ^ ((i >> 3) & 7));
        ((float4*)Vdst)[i] = ((const float4*)Vt)[sc];
    }
}

// ---------------- pass 2: attention, no main-loop barriers ----------------
// LDS (41728 B -> 3 blocks/CU):
//   [0,     16384) per-wave Q slabs [32][64] swz -> reused as per-wave wdiag [32][27] f32
//   [16384, 32768) per-wave P slabs (2 subs x [16][64] swz) -> reused as out2 bf16 [128][64]
//   [32768, 40192) per-wave qrel [32][29] bf16
//   [40192, 41728) lowL/highL/Linv [128] f32
__global__ __launch_bounds__(256, 3) void attn_kernel(
        const float* __restrict__ x,
        const float* __restrict__ tk,
        const float* __restrict__ tv,
        const u16t* __restrict__ wsK,
        const u16t* __restrict__ wsV,
        float* __restrict__ out) {
    __shared__ __align__(16) char smem[41728];

    const int tid = threadIdx.x;
    const int work = (blockIdx.x & 7) * (NBLK / 8) + (blockIdx.x >> 3);
    const int qt = work % NQT;
    const int h  = (work / NQT) % Hh;
    const int b  = work / (NQT * Hh);
    const int lane = tid & 63;
    const int w = tid >> 6;
    const int g = lane >> 4;
    const int c = lane & 15;
    const int q0 = qt * NQB;
    const int qw0 = q0 + w * 32;

    u16t* Qs     = (u16t*)(smem + w * 4096);            // [32][64] swz
    u16t* Ps     = (u16t*)(smem + 16384 + w * 4096);    // 2 x [16][64] swz
    float* wdiagw = (float*)(smem + w * 4096);          // [32][27] (overlays Qs after setup)
    u16t* qrelw  = (u16t*)(smem + 32768 + w * 1856);    // [32][29]
    float* lowL  = (float*)(smem + 40192);
    float* highL = lowL + 128;
    float* LinvA = lowL + 256;
    u16t* out2b  = (u16t*)(smem + 16384);               // [128][64] bf16 (overlays Ps)

    // ---- stage this wave's 32 Q rows as bf16 (swizzled), wave-local ----
    const float* xq = x + (size_t)b * Nn * C3 + h * 64;
    #pragma unroll
    for (int i = 0; i < 8; ++i) {
        int idx = lane + i * 64;          // 512 float4-chunks: row=idx>>4, d0=(idx&15)*4
        int row = idx >> 4;
        int d0 = (idx & 15) * 4;
        float4 v4 = *(const float4*)&xq[(size_t)(qw0 + row) * C3 + d0];
        ushort4 s4;
        s4.x = f2b(v4.x); s4.y = f2b(v4.y); s4.z = f2b(v4.z); s4.w = f2b(v4.w);
        *(ushort4*)&Qs[swz(row, d0)] = s4;
    }
    asm volatile("s_waitcnt lgkmcnt(0)" ::: "memory");

    // ---- Q fragments: A/B layout row=c, k=g*8+j ----
    bf16x8 qf[2][2];
    #pragma unroll
    for (int sub = 0; sub < 2; ++sub) {
        qf[sub][0] = *(const bf16x8*)&Qs[swz(sub * 16 + c, g * 8)];
        qf[sub][1] = *(const bf16x8*)&Qs[swz(sub * 16 + c, 32 + g * 8)];
    }

    // ---- qrel via MFMA: D[q = sub*16+g*4+r][t = tg*16+c] ----
    {
        bf16x8 tkf[2][2];
        #pragma unroll
        for (int tg = 0; tg < 2; ++tg) {
            int t = tg * 16 + c; t = t > 28 ? 28 : t;
            #pragma unroll
            for (int kh = 0; kh < 2; ++kh) {
                const float* tp = &tk[t * 64 + kh * 32 + g * 8];
                float4 a4 = *(const float4*)tp;
                float4 b4 = *(const float4*)(tp + 4);
                union { bf16x8 v; unsigned u[4]; } pk;
                pk.u[0] = pk2(a4.x, a4.y); pk.u[1] = pk2(a4.z, a4.w);
                pk.u[2] = pk2(b4.x, b4.y); pk.u[3] = pk2(b4.z, b4.w);
                tkf[tg][kh] = pk.v;
            }
        }
        #pragma unroll
        for (int sub = 0; sub < 2; ++sub) {
            #pragma unroll
            for (int tg = 0; tg < 2; ++tg) {
                f32x4 sr = {};
                sr = __builtin_amdgcn_mfma_f32_16x16x32_bf16(qf[sub][0], tkf[tg][0], sr, 0, 0, 0);
                sr = __builtin_amdgcn_mfma_f32_16x16x32_bf16(qf[sub][1], tkf[tg][1], sr, 0, 0, 0);
                int t = tg * 16 + c;
                if (t <= 28) {
                    #pragma unroll
                    for (int r = 0; r < 4; ++r)
                        qrelw[(sub * 16 + g * 4 + r) * NT + t] = f2b(sr[r]);
                }
            }
        }
    }
    asm volatile("s_waitcnt lgkmcnt(0)" ::: "memory");

    // ---- init wdiag (overlays Qs; Q reads complete) ----
    for (int i = lane; i < 32 * 27; i += 64) wdiagw[i] = 0.f;

    float qb0[2], qb28[2];
    #pragma unroll
    for (int sub = 0; sub < 2; ++sub) {
        int qrow = sub * 16 + c;
        qb0[sub]  = b2f(qrelw[qrow * NT + 0])  * KK_E;
        qb28[sub] = b2f(qrelw[qrow * NT + 28]) * KK_E;
    }

    const u16t* Kbase = wsK + (size_t)((b * Hh + h) * NKT) * TILE_ELEMS;
    const u16t* Vbase = wsV + (size_t)((b * Hh + h) * NKT) * TILE_ELEMS;

    f32x4 of[2][4] = {};
    float lowA[2] = {0.f, 0.f}, highA[2] = {0.f, 0.f};

    for (int kt = 0; kt < NKT; ++kt) {
        const u16t* Kt = Kbase + (size_t)kt * TILE_ELEMS;
        const u16t* Vt = Vbase + (size_t)kt * TILE_ELEMS;
        const int key0 = kt * KVBLK;
        #pragma unroll
        for (int ct = 0; ct < 4; ++ct) {
            bf16x8 kf0 = *(const bf16x8*)&Kt[(ct * 16 + c) * 64 + g * 8];
            bf16x8 kf1 = *(const bf16x8*)&Kt[(ct * 16 + c) * 64 + 32 + g * 8];
            #pragma unroll
            for (int sub = 0; sub < 2; ++sub) {
                f32x4 s = {};
                s = __builtin_amdgcn_mfma_f32_16x16x32_bf16(kf0, qf[sub][0], s, 0, 0, 0);
                s = __builtin_amdgcn_mfma_f32_16x16x32_bf16(kf1, qf[sub][1], s, 0, 0, 0);
                // lane holds S^T[key = key0+ct*16+g*4+r][q = qw0+sub*16+c]
                const int kb = key0 + ct * 16;
                const int qg0 = qw0 + sub * 16;
                float e[4];
                if (kb + 15 - qg0 <= -14) {
                    #pragma unroll
                    for (int r = 0; r < 4; ++r) {
                        e[r] = exp2f(fmaf(s[r], KK_E, qb0[sub]));
                        lowA[sub] += e[r];
                    }
                } else if (kb - qg0 - 15 >= 14) {
                    #pragma unroll
                    for (int r = 0; r < 4; ++r) {
                        e[r] = exp2f(fmaf(s[r], KK_E, qb28[sub]));
                        highA[sub] += e[r];
                    }
                } else {
                    const int qrow = sub * 16 + c;
                    const int qg = qg0 + c;
                    #pragma unroll
                    for (int r = 0; r < 4; ++r) {
                        int key = kb + g * 4 + r;
                        int delta = key - qg;
                        int t = delta + 14;
                        t = t < 0 ? 0 : (t > 28 ? 28 : t);
                        float bias = b2f(qrelw[qrow * NT + t]) * KK_E;
                        e[r] = exp2f(fmaf(s[r], KK_E, bias));
                        if (delta <= -14)      lowA[sub] += e[r];
                        else if (delta >= 14)  highA[sub] += e[r];
                        else                   wdiagw[qrow * 27 + delta + 13] = e[r];
                    }
                }
                uint2 pw;
                pw.x = pk2(e[0], e[1]);
                pw.y = pk2(e[2], e[3]);
                *(uint2*)&Ps[sub * 1024 + swz(c, ct * 16 + g * 4)] = pw;
            }
        }
        asm volatile("s_waitcnt lgkmcnt(0)" ::: "memory");   // P writes visible (wave-local)

        // ---- O^T += V^T . P^T (V fragments shared across the 2 q-streams) ----
        #pragma unroll
        for (int k0 = 0; k0 < 2; ++k0) {
            bf16x8 pf0 = *(const bf16x8*)&Ps[swz(c, k0 * 32 + g * 8)];
            bf16x8 pf1 = *(const bf16x8*)&Ps[1024 + swz(c, k0 * 32 + g * 8)];
            #pragma unroll
            for (int dt = 0; dt < 4; ++dt) {
                bf16x8 vf = *(const bf16x8*)&Vt[(dt * 16 + c) * 64 + k0 * 32 + g * 8];
                of[0][dt] = __builtin_amdgcn_mfma_f32_16x16x32_bf16(vf, pf0, of[0][dt], 0, 0, 0);
                of[1][dt] = __builtin_amdgcn_mfma_f32_16x16x32_bf16(vf, pf1, of[1][dt], 0, 0, 0);
            }
        }
    }

    // ---- reduce low/high across the 4 g-groups (same q=c) ----
    #pragma unroll
    for (int sub = 0; sub < 2; ++sub) {
        float lo = lowA[sub], hi = highA[sub];
        lo += __shfl_xor(lo, 16, 64);
        lo += __shfl_xor(lo, 32, 64);
        hi += __shfl_xor(hi, 16, 64);
        hi += __shfl_xor(hi, 32, 64);
        if (g == 0) {
            lowL[w * 32 + sub * 16 + c]  = lo;
            highL[w * 32 + sub * 16 + c] = hi;
        }
    }
    __syncthreads();

    // ---- out2[q][d] = sum_t w[t]*tv[t][d] (bf16); L = sum_t w[t] ----
    #pragma unroll
    for (int it = 0; it < 2; ++it) {
        int task = tid + it * 256;        // 512 tasks: q = task>>2, dp = (task&3)*16
        int q = task >> 2;
        int dp = (task & 3) * 16;
        float lo = lowL[q], hi = highL[q];
        float wsum = lo + hi;
        const float* wdq = (const float*)(smem + ((q >> 5) << 12)) + (q & 31) * 27;
        float acc[16];
        #pragma unroll
        for (int i4 = 0; i4 < 4; ++i4) {
            float4 ta = *(const float4*)&tv[dp + i4 * 4];
            float4 tb = *(const float4*)&tv[28 * 64 + dp + i4 * 4];
            acc[i4 * 4 + 0] = lo * ta.x + hi * tb.x;
            acc[i4 * 4 + 1] = lo * ta.y + hi * tb.y;
            acc[i4 * 4 + 2] = lo * ta.z + hi * tb.z;
            acc[i4 * 4 + 3] = lo * ta.w + hi * tb.w;
        }
        for (int t = 1; t <= 27; ++t) {
            float wv = wdq[t - 1];
            wsum += wv;
            #pragma unroll
            for (int i4 = 0; i4 < 4; ++i4) {
                float4 tr = *(const float4*)&tv[t * 64 + dp + i4 * 4];
                acc[i4 * 4 + 0] = fmaf(wv, tr.x, acc[i4 * 4 + 0]);
                acc[i4 * 4 + 1] = fmaf(wv, tr.y, acc[i4 * 4 + 1]);
                acc[i4 * 4 + 2] = fmaf(wv, tr.z, acc[i4 * 4 + 2]);
                acc[i4 * 4 + 3] = fmaf(wv, tr.w, acc[i4 * 4 + 3]);
            }
        }
        #pragma unroll
        for (int i = 0; i < 16; i += 2)
            *(unsigned*)&out2b[q * 64 + dp + i] = pk2(acc[i], acc[i + 1]);
        if ((task & 3) == 0) LinvA[q] = 1.f / wsum;
    }
    __syncthreads();

    // ---- epilogue: out[q][d] = (O^T[d][q] + out2[q][d]) / L[q] ----
    #pragma unroll
    for (int sub = 0; sub < 2; ++sub) {
        const int ql = w * 32 + sub * 16 + c;
        const float linv = LinvA[ql];
        float* orow = &out[((size_t)b * Nn + q0 + ql) * 768 + h * 64];
        #pragma unroll
        for (int dt = 0; dt < 4; ++dt) {
            const int d0 = dt * 16 + g * 4;
            float4 o4;
            o4.x = (of[sub][dt][0] + b2f(out2b[ql * 64 + d0 + 0])) * linv;
            o4.y = (of[sub][dt][1] + b2f(out2b[ql * 64 + d0 + 1])) * linv;
            o4.z = (of[sub][dt][2] + b2f(out2b[ql * 64 + d0 + 2])) * linv;
            o4.w = (of[sub][dt][3] + b2f(out2b[ql * 64 + d0 + 3])) * linv;
            *(float4*)&orow[d0] = o4;
        }
    }
}

extern "C" void kernel_launch(void* const* d_in, const int* in_sizes, int n_in,
                              void* d_out, int out_size, void* d_ws, size_t ws_size,
                              hipStream_t stream) {
    const float* x  = (const float*)d_in[0];
    const float* tk = (const float*)d_in[1];
    const float* tv = (const float*)d_in[2];
    float* out = (float*)d_out;
    u16t* wsK = (u16t*)d_ws;
    u16t* wsV = wsK + (size_t)Bb * Hh * NKT * TILE_ELEMS;
    preconv_kernel<<<dim3(Bb * Hh * NKT), dim3(256), 0, stream>>>(x, wsK, wsV);
    attn_kernel<<<dim3(NBLK), dim3(256), 0, stream>>>(x, tk, tv, wsK, wsV, out);
}

// Round 5
// 98.823 us; speedup vs baseline: 1.8906x; 1.8906x over previous
//
#include <hip/hip_runtime.h>
#include <hip/hip_bf16.h>

#define Bb 8
#define Nn 1024
#define Hh 12
#define C3 2304
#define KK_E 0.1803368801f   // (1/8) * log2(e)
#define NQB 128              // queries per block (4 waves x 32)
#define KVBLK 64
#define NT 29
#define NQT (Nn / NQB)       // 8
#define NKT (Nn / KVBLK)     // 16
#define NBLK (Bb * Hh * NQT) // 768
#define TILE_ELEMS 4096      // 64x64 bf16 tile

typedef short bf16x8 __attribute__((ext_vector_type(8)));
typedef float f32x16 __attribute__((ext_vector_type(16)));
typedef unsigned v2u __attribute__((ext_vector_type(2)));
typedef unsigned short u16t;

__device__ __forceinline__ float b2f(u16t v) {
    union { unsigned u; float f; } x; x.u = ((unsigned)v) << 16; return x.f;
}
__device__ __forceinline__ u16t f2b(float f) {
    union { float f; unsigned u; } x; x.f = f;
    unsigned r = x.u + 0x7fffu + ((x.u >> 16) & 1u);
    return (u16t)(r >> 16);
}
__device__ __forceinline__ unsigned pk2(float a, float b) {
    union { __hip_bfloat162 h; unsigned u; } cv;
    cv.h = __float22bfloat162_rn(make_float2(a, b));
    return cv.u;
}
// swizzled element index for row-major [rows][64] bf16 tiles (128B rows)
__device__ __forceinline__ int swz(int row, int col) {
    return (row * 64 + col) ^ ((row & 7) << 3);
}
// async global->LDS, 16B per lane; LDS dest is wave-uniform base (+lane*16 by HW)
__device__ __forceinline__ void gl_lds16(const void* g, void* l) {
    __builtin_amdgcn_global_load_lds(
        (const __attribute__((address_space(1))) unsigned int*)g,
        (__attribute__((address_space(3))) unsigned int*)l, 16, 0, 0);
}

// ---------------- pass 1: fp32 -> bf16, pre-swizzled K tiles + transposed V tiles ----
__global__ __launch_bounds__(256) void preconv_kernel(
        const float* __restrict__ x, u16t* __restrict__ wsK, u16t* __restrict__ wsV) {
    __shared__ __align__(16) u16t Vt[TILE_ELEMS];
    const int bid = blockIdx.x;                 // ((b*H + h)*NKT + kt)
    const int kt = bid % NKT;
    const int h  = (bid / NKT) % Hh;
    const int b  = bid / (NKT * Hh);
    const int tid = threadIdx.x;
    const float* xb = x + (size_t)b * Nn * C3 + (size_t)kt * KVBLK * C3 + 768 + h * 64;
    u16t* Kdst = wsK + (size_t)bid * TILE_ELEMS;
    u16t* Vdst = wsV + (size_t)bid * TILE_ELEMS;

    #pragma unroll
    for (int rep = 0; rep < 4; ++rep) {
        int idx = tid + rep * 256;
        int m = idx >> 4;
        int d0 = (idx & 15) * 4;
        const float* src = &xb[(size_t)m * C3 + d0];
        float4 k4 = *(const float4*)src;
        ushort4 s4;
        s4.x = f2b(k4.x); s4.y = f2b(k4.y); s4.z = f2b(k4.z); s4.w = f2b(k4.w);
        *(ushort4*)&Kdst[swz(m, d0)] = s4;      // swizzled [key][d]
        float4 v4 = *(const float4*)(src + 768);
        Vt[swz(d0 + 0, m)] = f2b(v4.x);         // swizzled transposed [d][key]
        Vt[swz(d0 + 1, m)] = f2b(v4.y);
        Vt[swz(d0 + 2, m)] = f2b(v4.z);
        Vt[swz(d0 + 3, m)] = f2b(v4.w);
    }
    __syncthreads();
    // linear 8KB copy of the already-swizzled transposed tile
    const float4* s = (const float4*)Vt;
    float4* d = (float4*)Vdst;
    d[tid] = s[tid];
    d[tid + 256] = s[tid + 256];
}

// ---------------- pass 2: attention ----------------
// LDS (50688 B -> 3 blocks/CU):
//   [0,     32768) K bufs (2x8KB) + V bufs (2x8KB)  -> [0,16384) reused as out2 bf16 [128][64]
//   [32768, 49152) per-wave 4KB slab: Q staging [32][64] -> {wdiag bf16 [32][27] @0,
//                                                            qrel bf16 [32][29] @1792}
//   [49152, 50688) lowL/highL/Linv [128] f32 each
__global__ __launch_bounds__(256, 3) void attn_kernel(
        const float* __restrict__ x,
        const float* __restrict__ tk,
        const float* __restrict__ tv,
        const u16t* __restrict__ wsK,
        const u16t* __restrict__ wsV,
        float* __restrict__ out) {
    __shared__ __align__(16) char smem[50688];

    const int tid = threadIdx.x;
    const int work = (blockIdx.x & 7) * (NBLK / 8) + (blockIdx.x >> 3);
    const int qt = work % NQT;
    const int h  = (work / NQT) % Hh;
    const int b  = work / (NQT * Hh);
    const int lane = tid & 63;
    const int w = tid >> 6;
    const int lq = lane & 31;
    const int hi = lane >> 5;
    const int q0 = qt * NQB;
    const int qw0 = q0 + w * 32;

    char* slab   = smem + 32768 + w * 4096;
    u16t* Qs     = (u16t*)slab;              // transient [32][64] swz
    u16t* wdiagw = (u16t*)slab;              // [32][27] bf16 (after prologue)
    u16t* qrelw  = (u16t*)(slab + 1792);     // [32][29] bf16
    float* lowL  = (float*)(smem + 49152);
    float* highL = (float*)(smem + 49664);
    float* LinvA = (float*)(smem + 50176);
    u16t* out2b  = (u16t*)smem;              // [128][64] bf16 after loop

    const char* KsrcB = (const char*)(wsK + (size_t)((b * Hh + h) * NKT) * TILE_ELEMS);
    const char* VsrcB = (const char*)(wsV + (size_t)((b * Hh + h) * NKT) * TILE_ELEMS);

    auto stage = [&](int t, int bufsel) {
        const char* Ks = KsrcB + (size_t)t * 8192;
        const char* Vs = VsrcB + (size_t)t * 8192;
        char* Kd = smem + bufsel * 8192;
        char* Vd = smem + 16384 + bufsel * 8192;
        #pragma unroll
        for (int i = 0; i < 2; ++i) {
            int off = w * 2048 + i * 1024;
            gl_lds16(Ks + off + lane * 16, Kd + off);
            gl_lds16(Vs + off + lane * 16, Vd + off);
        }
    };

    stage(0, 0);   // tile 0 in flight during the whole prologue

    // ---- stage this wave's 32 Q rows as bf16 (swizzled), wave-local ----
    const float* xq = x + (size_t)b * Nn * C3 + h * 64;
    #pragma unroll
    for (int i = 0; i < 8; ++i) {
        int idx = lane + i * 64;
        int row = idx >> 4;
        int d0 = (idx & 15) * 4;
        float4 v4 = *(const float4*)&xq[(size_t)(qw0 + row) * C3 + d0];
        ushort4 s4;
        s4.x = f2b(v4.x); s4.y = f2b(v4.y); s4.z = f2b(v4.z); s4.w = f2b(v4.w);
        *(ushort4*)&Qs[swz(row, d0)] = s4;
    }

    // ---- Q fragments (A/B layout: row/col = lq, k = hi*8+j per 16-k slot) ----
    bf16x8 qB[4];
    #pragma unroll
    for (int slot = 0; slot < 4; ++slot)
        qB[slot] = *(const bf16x8*)&Qs[swz(lq, slot * 16 + hi * 8)];

    // ---- qrel[q][t] = Q[q,:].tk[t,:] via 4 MFMAs: D[q=crow(reg,hi)][t=lq] ----
    {
        const int tc = lq > 28 ? 28 : lq;
        f32x16 qr = {};
        #pragma unroll
        for (int slot = 0; slot < 4; ++slot) {
            const float* tp = &tk[tc * 64 + slot * 16 + hi * 8];
            float4 a4 = *(const float4*)tp;
            float4 b4 = *(const float4*)(tp + 4);
            union { bf16x8 v; unsigned u[4]; } pk;
            pk.u[0] = pk2(a4.x, a4.y); pk.u[1] = pk2(a4.z, a4.w);
            pk.u[2] = pk2(b4.x, b4.y); pk.u[3] = pk2(b4.z, b4.w);
            qr = __builtin_amdgcn_mfma_f32_32x32x16_bf16(qB[slot], pk.v, qr, 0, 0, 0);
        }
        if (lq <= 28) {
            #pragma unroll
            for (int reg = 0; reg < 16; ++reg) {
                int qrow = (reg & 3) + 8 * (reg >> 2) + 4 * hi;
                qrelw[qrow * NT + lq] = f2b(qr[reg]);
            }
        }
    }
    // zero wdiag (overlays Q slab; Q already in regs, compiler orders LDS ops)
    for (int i = lane; i < 432; i += 64) ((unsigned*)wdiagw)[i] = 0u;

    const float qb0  = b2f(qrelw[lq * NT + 0])  * KK_E;
    const float qb28 = b2f(qrelw[lq * NT + 28]) * KK_E;

    stage(1, 1);   // tile 1 stays in flight across the entry barrier
    asm volatile("s_waitcnt vmcnt(4)" ::: "memory");   // tile 0 landed
    asm volatile("s_barrier" ::: "memory");

    f32x16 of[2] = {};
    float lowA = 0.f, highA = 0.f;

    for (int kt = 0; kt < NKT; ++kt) {
        const int cursel = kt & 1;
        const u16t* K_ = (const u16t*)(smem + cursel * 8192);
        const u16t* V_ = (const u16t*)(smem + 16384 + cursel * 8192);
        const int key00 = kt * KVBLK;

        #pragma unroll
        for (int kb = 0; kb < 2; ++kb) {
            f32x16 s = {};
            #pragma unroll
            for (int slot = 0; slot < 4; ++slot) {
                bf16x8 kf = *(const bf16x8*)&K_[swz(kb * 32 + lq, slot * 16 + hi * 8)];
                s = __builtin_amdgcn_mfma_f32_32x32x16_bf16(kf, qB[slot], s, 0, 0, 0);
            }
            // lane holds S^T[key = kbase + (r&3)+8*(r>>2)+4*hi][q = qw0+lq]
            const int kbase = key00 + kb * 32;
            float e[16];
            if (kbase + 31 - qw0 <= -14) {
                #pragma unroll
                for (int r = 0; r < 16; ++r) {
                    e[r] = exp2f(fmaf(s[r], KK_E, qb0));
                    lowA += e[r];
                }
            } else if (kbase - (qw0 + 31) >= 14) {
                #pragma unroll
                for (int r = 0; r < 16; ++r) {
                    e[r] = exp2f(fmaf(s[r], KK_E, qb28));
                    highA += e[r];
                }
            } else {
                const int qg = qw0 + lq;
                #pragma unroll
                for (int r = 0; r < 16; ++r) {
                    int key = kbase + (r & 3) + 8 * (r >> 2) + 4 * hi;
                    int delta = key - qg;
                    int t = delta + 14;
                    t = t < 0 ? 0 : (t > 28 ? 28 : t);
                    float bias = b2f(qrelw[lq * NT + t]) * KK_E;
                    e[r] = exp2f(fmaf(s[r], KK_E, bias));
                    if (delta <= -14)      lowA += e[r];
                    else if (delta >= 14)  highA += e[r];
                    else                   wdiagw[lq * 27 + delta + 13] = f2b(e[r]);
                }
            }
            // T12: pack + permlane32_swap -> PV B-frags in registers (no LDS)
            unsigned A0 = pk2(e[0],  e[1]),  B0 = pk2(e[2],  e[3]);
            unsigned C0 = pk2(e[4],  e[5]),  D0 = pk2(e[6],  e[7]);
            unsigned A1 = pk2(e[8],  e[9]),  B1 = pk2(e[10], e[11]);
            unsigned C1 = pk2(e[12], e[13]), D1 = pk2(e[14], e[15]);
            v2u r0 = __builtin_amdgcn_permlane32_swap(A0, C0, false, false);
            v2u r1 = __builtin_amdgcn_permlane32_swap(B0, D0, false, false);
            v2u r2 = __builtin_amdgcn_permlane32_swap(A1, C1, false, false);
            v2u r3 = __builtin_amdgcn_permlane32_swap(B1, D1, false, false);
            union { bf16x8 v; unsigned u[4]; } pf0, pf1;
            pf0.u[0] = r0[0]; pf0.u[1] = r1[0]; pf0.u[2] = r0[1]; pf0.u[3] = r1[1];
            pf1.u[0] = r2[0]; pf1.u[1] = r3[0]; pf1.u[2] = r2[1]; pf1.u[3] = r3[1];
            // O^T += V^T . P^T : A = V^T[d=db*32+lq][key], B = P-frag
            #pragma unroll
            for (int db = 0; db < 2; ++db) {
                bf16x8 vf0 = *(const bf16x8*)&V_[swz(db * 32 + lq, (kb * 2 + 0) * 16 + hi * 8)];
                bf16x8 vf1 = *(const bf16x8*)&V_[swz(db * 32 + lq, (kb * 2 + 1) * 16 + hi * 8)];
                of[db] = __builtin_amdgcn_mfma_f32_32x32x16_bf16(vf0, pf0.v, of[db], 0, 0, 0);
                of[db] = __builtin_amdgcn_mfma_f32_32x32x16_bf16(vf1, pf1.v, of[db], 0, 0, 0);
            }
        }

        asm volatile("s_barrier" ::: "memory");          // all waves done reading buf
        if (kt + 2 < NKT) {
            stage(kt + 2, cursel);                       // prefetch into just-freed buf
            asm volatile("s_waitcnt vmcnt(4)" ::: "memory");  // tile kt+1 landed, kt+2 in flight
        } else {
            asm volatile("s_waitcnt vmcnt(0)" ::: "memory");
        }
        asm volatile("s_barrier" ::: "memory");          // all waves' loads visible
    }

    // ---- reduce low/high across hi halves (lanes l, l+32 share q) ----
    lowA  += __shfl_xor(lowA, 32, 64);
    highA += __shfl_xor(highA, 32, 64);
    if (hi == 0) { lowL[w * 32 + lq] = lowA; highL[w * 32 + lq] = highA; }
    __syncthreads();

    // ---- out2[q][d] = sum_t w[t]*tv[t][d]; L = sum_t w[t] ----
    {
        const int q = tid >> 1;
        const int dp = (tid & 1) * 32;
        float lo = lowL[q], hh = highL[q];
        float wsum = lo + hh;
        const u16t* wdq = (const u16t*)(smem + 32768 + (q >> 5) * 4096) + (q & 31) * 27;
        float acc[32];
        #pragma unroll
        for (int i4 = 0; i4 < 8; ++i4) {
            float4 ta = *(const float4*)&tv[dp + i4 * 4];
            float4 tb = *(const float4*)&tv[28 * 64 + dp + i4 * 4];
            acc[i4 * 4 + 0] = lo * ta.x + hh * tb.x;
            acc[i4 * 4 + 1] = lo * ta.y + hh * tb.y;
            acc[i4 * 4 + 2] = lo * ta.z + hh * tb.z;
            acc[i4 * 4 + 3] = lo * ta.w + hh * tb.w;
        }
        for (int t = 1; t <= 27; ++t) {
            float wv = b2f(wdq[t - 1]);
            wsum += wv;
            #pragma unroll
            for (int i4 = 0; i4 < 8; ++i4) {
                float4 tr = *(const float4*)&tv[t * 64 + dp + i4 * 4];
                acc[i4 * 4 + 0] = fmaf(wv, tr.x, acc[i4 * 4 + 0]);
                acc[i4 * 4 + 1] = fmaf(wv, tr.y, acc[i4 * 4 + 1]);
                acc[i4 * 4 + 2] = fmaf(wv, tr.z, acc[i4 * 4 + 2]);
                acc[i4 * 4 + 3] = fmaf(wv, tr.w, acc[i4 * 4 + 3]);
            }
        }
        #pragma unroll
        for (int i = 0; i < 32; i += 2)
            *(unsigned*)&out2b[q * 64 + dp + i] = pk2(acc[i], acc[i + 1]);
        if ((tid & 1) == 0) LinvA[q] = 1.f / wsum;
    }
    __syncthreads();

    // ---- epilogue: out[q][d] = (O^T[d][q] + out2[q][d]) / L[q] ----
    {
        const int ql = w * 32 + lq;
        const float linv = LinvA[ql];
        float* orow = &out[((size_t)b * Nn + q0 + ql) * 768 + h * 64];
        #pragma unroll
        for (int db = 0; db < 2; ++db) {
            #pragma unroll
            for (int rq = 0; rq < 4; ++rq) {
                int d0 = db * 32 + 8 * rq + 4 * hi;
                const u16t* o2 = &out2b[ql * 64 + d0];
                float4 o4;
                o4.x = (of[db][rq * 4 + 0] + b2f(o2[0])) * linv;
                o4.y = (of[db][rq * 4 + 1] + b2f(o2[1])) * linv;
                o4.z = (of[db][rq * 4 + 2] + b2f(o2[2])) * linv;
                o4.w = (of[db][rq * 4 + 3] + b2f(o2[3])) * linv;
                *(float4*)&orow[d0] = o4;
            }
        }
    }
}

extern "C" void kernel_launch(void* const* d_in, const int* in_sizes, int n_in,
                              void* d_out, int out_size, void* d_ws, size_t ws_size,
                              hipStream_t stream) {
    const float* x  = (const float*)d_in[0];
    const float* tk = (const float*)d_in[1];
    const float* tv = (const float*)d_in[2];
    float* out = (float*)d_out;
    u16t* wsK = (u16t*)d_ws;
    u16t* wsV = wsK + (size_t)Bb * Hh * NKT * TILE_ELEMS;
    preconv_kernel<<<dim3(Bb * Hh * NKT), dim3(256), 0, stream>>>(x, wsK, wsV);
    attn_kernel<<<dim3(NBLK), dim3(256), 0, stream>>>(x, tk, tv, wsK, wsV, out);
}

// Round 6
// 97.292 us; speedup vs baseline: 1.9203x; 1.0157x over previous
//
#include <hip/hip_runtime.h>
#include <hip/hip_bf16.h>

#define Bb 8
#define Nn 1024
#define Hh 12
#define C3 2304
#define KK_E 0.1803368801f   // (1/8) * log2(e)
#define NQB 128              // queries per block (4 waves x 32)
#define KVBLK 64
#define NT 29
#define NQT (Nn / NQB)       // 8
#define NKT (Nn / KVBLK)     // 16
#define NBLK (Bb * Hh * NQT) // 768
#define TILE_ELEMS 4096      // 64x64 bf16 tile

typedef short bf16x8 __attribute__((ext_vector_type(8)));
typedef float f32x16 __attribute__((ext_vector_type(16)));
typedef unsigned v2u __attribute__((ext_vector_type(2)));
typedef unsigned short u16t;

__device__ __forceinline__ float b2f(u16t v) {
    union { unsigned u; float f; } x; x.u = ((unsigned)v) << 16; return x.f;
}
__device__ __forceinline__ u16t f2b(float f) {
    union { float f; unsigned u; } x; x.f = f;
    unsigned r = x.u + 0x7fffu + ((x.u >> 16) & 1u);
    return (u16t)(r >> 16);
}
// single-instruction packed f32->bf16 (T12): dst.lo=bf16(a), dst.hi=bf16(b)
__device__ __forceinline__ unsigned pk2a(float a, float b) {
    unsigned r;
    asm("v_cvt_pk_bf16_f32 %0, %1, %2" : "=v"(r) : "v"(a), "v"(b));
    return r;
}
// async global->LDS, 16B per lane; LDS dest is wave-uniform base (+lane*16 by HW)
__device__ __forceinline__ void gl_lds16(const void* g, void* l) {
    __builtin_amdgcn_global_load_lds(
        (const __attribute__((address_space(1))) unsigned int*)g,
        (__attribute__((address_space(3))) unsigned int*)l, 16, 0, 0);
}

// ---------------- pass 1: fp32 -> bf16 in FRAG-LINEAR tile layout ----------------
// K tile (8KB): u16 idx = (key&31)*8 + (key>>5)*256 + ((d>>3)&1)*512 + (d>>4)*1024 + (d&7)
// V tile (8KB): u16 idx = (d&31)*8 + ((d>>5)&1)*256 + ((key>>3)&1)*512 + (key>>4)*1024 + (key&7)
// -> every MFMA fragment is 64 consecutive 16B chunks (conflict-free ds_read_b128)
__global__ __launch_bounds__(256) void preconv_kernel(
        const float* __restrict__ x, u16t* __restrict__ wsK, u16t* __restrict__ wsV) {
    __shared__ __align__(16) u16t Vt[TILE_ELEMS];
    const int bid = blockIdx.x;                 // ((b*H + h)*NKT + kt)
    const int kt = bid % NKT;
    const int h  = (bid / NKT) % Hh;
    const int b  = bid / (NKT * Hh);
    const int tid = threadIdx.x;
    const float* xb = x + (size_t)b * Nn * C3 + (size_t)kt * KVBLK * C3 + 768 + h * 64;
    u16t* Kdst = wsK + (size_t)bid * TILE_ELEMS;
    u16t* Vdst = wsV + (size_t)bid * TILE_ELEMS;

    #pragma unroll
    for (int rep = 0; rep < 4; ++rep) {
        int idx = tid + rep * 256;
        int m = idx >> 4;               // key 0..63
        int d0 = (idx & 15) * 4;        // d0 in {0,4,...,60}
        const float* src = &xb[(size_t)m * C3 + d0];
        float4 k4 = *(const float4*)src;
        uint2 kp;
        kp.x = pk2a(k4.x, k4.y);
        kp.y = pk2a(k4.z, k4.w);
        int ko = (m & 31) * 8 + (m >> 5) * 256 + ((d0 >> 3) & 1) * 512
               + (d0 >> 4) * 1024 + (d0 & 7);
        *(uint2*)&Kdst[ko] = kp;        // direct global, 8B aligned
        float4 v4 = *(const float4*)(src + 768);
        int vb = ((m >> 3) & 1) * 512 + (m >> 4) * 1024 + (m & 7);
        Vt[((d0 + 0) & 31) * 8 + (((d0 + 0) >> 5) & 1) * 256 + vb] = f2b(v4.x);
        Vt[((d0 + 1) & 31) * 8 + (((d0 + 1) >> 5) & 1) * 256 + vb] = f2b(v4.y);
        Vt[((d0 + 2) & 31) * 8 + (((d0 + 2) >> 5) & 1) * 256 + vb] = f2b(v4.z);
        Vt[((d0 + 3) & 31) * 8 + (((d0 + 3) >> 5) & 1) * 256 + vb] = f2b(v4.w);
    }
    __syncthreads();
    // tile already frag-linear in LDS: plain linear copy-out
    const float4* s = (const float4*)Vt;
    float4* d = (float4*)Vdst;
    d[tid] = s[tid];
    d[tid + 256] = s[tid + 256];
}

// ---------------- pass 2: attention ----------------
// LDS (50688 B -> 3 blocks/CU):
//   [0,     32768) K bufs @0,8192 ; V bufs @16384,24576 -> [0,16384) reused as out2 bf16
//   [32768, 49152) per-wave 4KB slab: Q frag-linear staging -> {wdiag bf16 [32][27] @0,
//                                                               qrel bf16 [32][29] @2048}
//   [49152, 50688) lowL/highL/Linv [128] f32 each
__global__ __launch_bounds__(256, 3) void attn_kernel(
        const float* __restrict__ x,
        const float* __restrict__ tk,
        const float* __restrict__ tv,
        const u16t* __restrict__ wsK,
        const u16t* __restrict__ wsV,
        float* __restrict__ out) {
    __shared__ __align__(16) char smem[50688];

    const int tid = threadIdx.x;
    const int work = (blockIdx.x & 7) * (NBLK / 8) + (blockIdx.x >> 3);
    const int qt = work % NQT;
    const int h  = (work / NQT) % Hh;
    const int b  = work / (NQT * Hh);
    const int lane = tid & 63;
    const int w = tid >> 6;
    const int lq = lane & 31;
    const int hi = lane >> 5;
    const int q0 = qt * NQB;
    const int qw0 = q0 + w * 32;

    char* slab   = smem + 32768 + w * 4096;
    u16t* Qs     = (u16t*)slab;              // transient frag-linear [2048]
    u16t* wdiagw = (u16t*)slab;              // [32][27] bf16 (after prologue)
    u16t* qrelw  = (u16t*)(slab + 2048);     // [32][29] bf16
    float* lowL  = (float*)(smem + 49152);
    float* highL = (float*)(smem + 49664);
    float* LinvA = (float*)(smem + 50176);
    u16t* out2b  = (u16t*)smem;              // [128][64] bf16 after loop

    const char* KsrcB = (const char*)(wsK + (size_t)((b * Hh + h) * NKT) * TILE_ELEMS);
    const char* VsrcB = (const char*)(wsV + (size_t)((b * Hh + h) * NKT) * TILE_ELEMS);

    auto stage = [&](int t, int bufsel) {
        const char* Ks = KsrcB + (size_t)t * 8192;
        const char* Vs = VsrcB + (size_t)t * 8192;
        char* Kd = smem + bufsel * 8192;
        char* Vd = smem + 16384 + bufsel * 8192;
        #pragma unroll
        for (int i = 0; i < 2; ++i) {
            int off = w * 2048 + i * 1024;
            gl_lds16(Ks + off + lane * 16, Kd + off);
            gl_lds16(Vs + off + lane * 16, Vd + off);
        }
    };

    stage(0, 0);   // tile 0 in flight during the whole prologue

    // ---- stage this wave's 32 Q rows, PRE-SCALED by KK_E, frag-linear ----
    const float* xq = x + (size_t)b * Nn * C3 + h * 64;
    #pragma unroll
    for (int i = 0; i < 8; ++i) {
        int idx = lane + i * 64;
        int row = idx >> 4;
        int d0 = (idx & 15) * 4;
        float4 v4 = *(const float4*)&xq[(size_t)(qw0 + row) * C3 + d0];
        uint2 qp;
        qp.x = pk2a(v4.x * KK_E, v4.y * KK_E);
        qp.y = pk2a(v4.z * KK_E, v4.w * KK_E);
        int qo = row * 8 + ((d0 >> 3) & 1) * 256 + (d0 >> 4) * 512 + (d0 & 7);
        *(uint2*)&Qs[qo] = qp;
    }

    // ---- Q fragments: one vaddr + imm offsets ----
    const u16t* Qv = Qs + lq * 8 + hi * 256;
    bf16x8 qB[4];
    #pragma unroll
    for (int slot = 0; slot < 4; ++slot)
        qB[slot] = *(const bf16x8*)&Qv[slot * 512];

    // ---- qrel[q][t] = (KK_E*Q[q,:]).tk[t,:] via 4 MFMAs: D[q=crow(reg,hi)][t=lq] ----
    {
        const int tc = lq > 28 ? 28 : lq;
        f32x16 qr = {};
        #pragma unroll
        for (int slot = 0; slot < 4; ++slot) {
            const float* tp = &tk[tc * 64 + slot * 16 + hi * 8];
            float4 a4 = *(const float4*)tp;
            float4 b4 = *(const float4*)(tp + 4);
            union { bf16x8 v; unsigned u[4]; } pk;
            pk.u[0] = pk2a(a4.x, a4.y); pk.u[1] = pk2a(a4.z, a4.w);
            pk.u[2] = pk2a(b4.x, b4.y); pk.u[3] = pk2a(b4.z, b4.w);
            qr = __builtin_amdgcn_mfma_f32_32x32x16_bf16(qB[slot], pk.v, qr, 0, 0, 0);
        }
        if (lq <= 28) {
            #pragma unroll
            for (int reg = 0; reg < 16; ++reg) {
                int qrow = (reg & 3) + 8 * (reg >> 2) + 4 * hi;
                qrelw[qrow * NT + lq] = f2b(qr[reg]);
            }
        }
    }
    // zero wdiag (overlays Q slab; Q already consumed into regs; same-wave LDS is in-order)
    for (int i = lane; i < 432; i += 64) ((unsigned*)wdiagw)[i] = 0u;

    const float qb0  = b2f(qrelw[lq * NT + 0]);    // already scaled
    const float qb28 = b2f(qrelw[lq * NT + 28]);

    stage(1, 1);   // tile 1 stays in flight across the entry barrier
    asm volatile("s_waitcnt vmcnt(4)" ::: "memory");   // tile 0 landed
    asm volatile("s_barrier" ::: "memory");

    f32x16 of[2] = {};
    float lowA = 0.f, highA = 0.f;

    for (int kt = 0; kt < NKT; ++kt) {
        const int cursel = kt & 1;
        const u16t* Kv = (const u16t*)(smem + cursel * 8192) + lq * 8 + hi * 512;
        const u16t* Vv = (const u16t*)(smem + 16384 + cursel * 8192) + lq * 8 + hi * 512;
        const int key00 = kt * KVBLK;

        #pragma unroll
        for (int kb = 0; kb < 2; ++kb) {
            const int kbase = key00 + kb * 32;
            const bool flo = (kbase + 31 - qw0 <= -14);
            const bool fhi = (kbase - (qw0 + 31) >= 14);
            const float binit = flo ? qb0 : (fhi ? qb28 : 0.f);
            f32x16 s;
            #pragma unroll
            for (int r = 0; r < 16; ++r) s[r] = binit;   // bias folded into C-init
            __builtin_amdgcn_s_setprio(1);
            #pragma unroll
            for (int slot = 0; slot < 4; ++slot) {
                bf16x8 kf = *(const bf16x8*)&Kv[kb * 256 + slot * 1024];
                s = __builtin_amdgcn_mfma_f32_32x32x16_bf16(kf, qB[slot], s, 0, 0, 0);
            }
            __builtin_amdgcn_s_setprio(0);
            // lane holds S^T[key = kbase+(r&3)+8*(r>>2)+4*hi][q = qw0+lq] (+bias)
            float e[16];
            if (flo || fhi) {
                #pragma unroll
                for (int r = 0; r < 16; ++r) e[r] = exp2f(s[r]);
                float a0 = (e[0]+e[1]) + (e[2]+e[3]);
                float a1 = (e[4]+e[5]) + (e[6]+e[7]);
                float a2 = (e[8]+e[9]) + (e[10]+e[11]);
                float a3 = (e[12]+e[13]) + (e[14]+e[15]);
                float at = (a0+a1) + (a2+a3);
                if (flo) lowA += at; else highA += at;
            } else {
                const int qg = qw0 + lq;
                #pragma unroll
                for (int r = 0; r < 16; ++r) {
                    int key = kbase + (r & 3) + 8 * (r >> 2) + 4 * hi;
                    int delta = key - qg;
                    int t = delta + 14;
                    t = t < 0 ? 0 : (t > 28 ? 28 : t);
                    e[r] = exp2f(s[r] + b2f(qrelw[lq * NT + t]));
                    if (delta <= -14)      lowA += e[r];
                    else if (delta >= 14)  highA += e[r];
                    else                   wdiagw[lq * 27 + delta + 13] = f2b(e[r]);
                }
            }
            // T12: cvt_pk + permlane32_swap -> PV B-frags in registers (no LDS)
            unsigned A0 = pk2a(e[0],  e[1]),  B0 = pk2a(e[2],  e[3]);
            unsigned C0 = pk2a(e[4],  e[5]),  D0 = pk2a(e[6],  e[7]);
            unsigned A1 = pk2a(e[8],  e[9]),  B1 = pk2a(e[10], e[11]);
            unsigned C1 = pk2a(e[12], e[13]), D1 = pk2a(e[14], e[15]);
            v2u r0 = __builtin_amdgcn_permlane32_swap(A0, C0, false, false);
            v2u r1 = __builtin_amdgcn_permlane32_swap(B0, D0, false, false);
            v2u r2 = __builtin_amdgcn_permlane32_swap(A1, C1, false, false);
            v2u r3 = __builtin_amdgcn_permlane32_swap(B1, D1, false, false);
            union { bf16x8 v; unsigned u[4]; } pf0, pf1;
            pf0.u[0] = r0[0]; pf0.u[1] = r1[0]; pf0.u[2] = r0[1]; pf0.u[3] = r1[1];
            pf1.u[0] = r2[0]; pf1.u[1] = r3[0]; pf1.u[2] = r2[1]; pf1.u[3] = r3[1];
            __builtin_amdgcn_s_setprio(1);
            #pragma unroll
            for (int db = 0; db < 2; ++db) {
                bf16x8 vf0 = *(const bf16x8*)&Vv[db * 256 + (kb * 2 + 0) * 1024];
                bf16x8 vf1 = *(const bf16x8*)&Vv[db * 256 + (kb * 2 + 1) * 1024];
                of[db] = __builtin_amdgcn_mfma_f32_32x32x16_bf16(vf0, pf0.v, of[db], 0, 0, 0);
                of[db] = __builtin_amdgcn_mfma_f32_32x32x16_bf16(vf1, pf1.v, of[db], 0, 0, 0);
            }
            __builtin_amdgcn_s_setprio(0);
        }

        asm volatile("s_barrier" ::: "memory");          // all waves done reading buf
        if (kt + 2 < NKT) {
            stage(kt + 2, cursel);                       // prefetch into just-freed buf
            asm volatile("s_waitcnt vmcnt(4)" ::: "memory");  // kt+1 landed, kt+2 in flight
        } else {
            asm volatile("s_waitcnt vmcnt(0)" ::: "memory");
        }
        asm volatile("s_barrier" ::: "memory");          // all waves' loads visible
    }

    // ---- reduce low/high across hi halves (lanes l, l+32 share q) ----
    lowA  += __shfl_xor(lowA, 32, 64);
    highA += __shfl_xor(highA, 32, 64);
    if (hi == 0) { lowL[w * 32 + lq] = lowA; highL[w * 32 + lq] = highA; }
    __syncthreads();

    // ---- out2[q][d] = sum_t w[t]*tv[t][d]; L = sum_t w[t] ----
    {
        const int q = tid >> 1;
        const int dp = (tid & 1) * 32;
        float lo = lowL[q], hh = highL[q];
        float wsum = lo + hh;
        const u16t* wdq = (const u16t*)(smem + 32768 + (q >> 5) * 4096) + (q & 31) * 27;
        float acc[32];
        #pragma unroll
        for (int i4 = 0; i4 < 8; ++i4) {
            float4 ta = *(const float4*)&tv[dp + i4 * 4];
            float4 tb = *(const float4*)&tv[28 * 64 + dp + i4 * 4];
            acc[i4 * 4 + 0] = lo * ta.x + hh * tb.x;
            acc[i4 * 4 + 1] = lo * ta.y + hh * tb.y;
            acc[i4 * 4 + 2] = lo * ta.z + hh * tb.z;
            acc[i4 * 4 + 3] = lo * ta.w + hh * tb.w;
        }
        for (int t = 1; t <= 27; ++t) {
            float wv = b2f(wdq[t - 1]);
            wsum += wv;
            #pragma unroll
            for (int i4 = 0; i4 < 8; ++i4) {
                float4 tr = *(const float4*)&tv[t * 64 + dp + i4 * 4];
                acc[i4 * 4 + 0] = fmaf(wv, tr.x, acc[i4 * 4 + 0]);
                acc[i4 * 4 + 1] = fmaf(wv, tr.y, acc[i4 * 4 + 1]);
                acc[i4 * 4 + 2] = fmaf(wv, tr.z, acc[i4 * 4 + 2]);
                acc[i4 * 4 + 3] = fmaf(wv, tr.w, acc[i4 * 4 + 3]);
            }
        }
        #pragma unroll
        for (int i = 0; i < 32; i += 2)
            *(unsigned*)&out2b[q * 64 + dp + i] = pk2a(acc[i], acc[i + 1]);
        if ((tid & 1) == 0) LinvA[q] = 1.f / wsum;
    }
    __syncthreads();

    // ---- epilogue: out[q][d] = (O^T[d][q] + out2[q][d]) / L[q] ----
    {
        const int ql = w * 32 + lq;
        const float linv = LinvA[ql];
        float* orow = &out[((size_t)b * Nn + q0 + ql) * 768 + h * 64];
        #pragma unroll
        for (int db = 0; db < 2; ++db) {
            #pragma unroll
            for (int rq = 0; rq < 4; ++rq) {
                int d0 = db * 32 + 8 * rq + 4 * hi;
                const u16t* o2 = &out2b[ql * 64 + d0];
                float4 o4;
                o4.x = (of[db][rq * 4 + 0] + b2f(o2[0])) * linv;
                o4.y = (of[db][rq * 4 + 1] + b2f(o2[1])) * linv;
                o4.z = (of[db][rq * 4 + 2] + b2f(o2[2])) * linv;
                o4.w = (of[db][rq * 4 + 3] + b2f(o2[3])) * linv;
                *(float4*)&orow[d0] = o4;
            }
        }
    }
}

extern "C" void kernel_launch(void* const* d_in, const int* in_sizes, int n_in,
                              void* d_out, int out_size, void* d_ws, size_t ws_size,
                              hipStream_t stream) {
    const float* x  = (const float*)d_in[0];
    const float* tk = (const float*)d_in[1];
    const float* tv = (const float*)d_in[2];
    float* out = (float*)d_out;
    u16t* wsK = (u16t*)d_ws;
    u16t* wsV = wsK + (size_t)Bb * Hh * NKT * TILE_ELEMS;
    preconv_kernel<<<dim3(Bb * Hh * NKT), dim3(256), 0, stream>>>(x, wsK, wsV);
    attn_kernel<<<dim3(NBLK), dim3(256), 0, stream>>>(x, tk, tv, wsK, wsV, out);
}

// Round 7
// 83.631 us; speedup vs baseline: 2.2340x; 1.1633x over previous
//
#include <hip/hip_runtime.h>
#include <hip/hip_bf16.h>

#define Bb 8
#define Nn 1024
#define Hh 12
#define C3 2304
#define KK_E 0.1803368801f   // (1/8) * log2(e)
#define NQB 128              // queries per block (4 waves x 32)
#define KVBLK 64
#define NT 29
#define NQT (Nn / NQB)       // 8
#define NKT (Nn / KVBLK)     // 16
#define NBLK (Bb * Hh * NQT) // 768
#define TILE_ELEMS 4096      // 64x64 bf16 tile

typedef short bf16x8 __attribute__((ext_vector_type(8)));
typedef float f32x16 __attribute__((ext_vector_type(16)));
typedef unsigned v2u __attribute__((ext_vector_type(2)));
typedef unsigned short u16t;

__device__ __forceinline__ float b2f(u16t v) {
    union { unsigned u; float f; } x; x.u = ((unsigned)v) << 16; return x.f;
}
__device__ __forceinline__ u16t f2b(float f) {
    union { float f; unsigned u; } x; x.f = f;
    unsigned r = x.u + 0x7fffu + ((x.u >> 16) & 1u);
    return (u16t)(r >> 16);
}
// single-instruction packed f32->bf16 (T12): dst.lo=bf16(a), dst.hi=bf16(b)
__device__ __forceinline__ unsigned pk2a(float a, float b) {
    unsigned r;
    asm("v_cvt_pk_bf16_f32 %0, %1, %2" : "=v"(r) : "v"(a), "v"(b));
    return r;
}

// ---------------- pass 1: fp32 -> bf16 in FRAG-LINEAR tile layout ----------------
// K tile (8KB): u16 idx = (key&31)*8 + (key>>5)*256 + ((d>>3)&1)*512 + (d>>4)*1024 + (d&7)
// V tile (8KB): u16 idx = (d&31)*8 + ((d>>5)&1)*256 + ((key>>3)&1)*512 + (key>>4)*1024 + (key&7)
// -> every MFMA fragment is 64 consecutive 16B chunks (one coalesced dwordx4 per lane)
__global__ __launch_bounds__(256) void preconv_kernel(
        const float* __restrict__ x, u16t* __restrict__ wsK, u16t* __restrict__ wsV) {
    __shared__ __align__(16) u16t Vt[TILE_ELEMS];
    const int bid = blockIdx.x;                 // ((b*H + h)*NKT + kt)
    const int kt = bid % NKT;
    const int h  = (bid / NKT) % Hh;
    const int b  = bid / (NKT * Hh);
    const int tid = threadIdx.x;
    const float* xb = x + (size_t)b * Nn * C3 + (size_t)kt * KVBLK * C3 + 768 + h * 64;
    u16t* Kdst = wsK + (size_t)bid * TILE_ELEMS;
    u16t* Vdst = wsV + (size_t)bid * TILE_ELEMS;

    #pragma unroll
    for (int rep = 0; rep < 4; ++rep) {
        int idx = tid + rep * 256;
        int m = idx >> 4;               // key 0..63
        int d0 = (idx & 15) * 4;        // d0 in {0,4,...,60}
        const float* src = &xb[(size_t)m * C3 + d0];
        float4 k4 = *(const float4*)src;
        uint2 kp;
        kp.x = pk2a(k4.x, k4.y);
        kp.y = pk2a(k4.z, k4.w);
        int ko = (m & 31) * 8 + (m >> 5) * 256 + ((d0 >> 3) & 1) * 512
               + (d0 >> 4) * 1024 + (d0 & 7);
        *(uint2*)&Kdst[ko] = kp;        // direct global, 8B aligned
        float4 v4 = *(const float4*)(src + 768);
        int vb = ((m >> 3) & 1) * 512 + (m >> 4) * 1024 + (m & 7);
        Vt[((d0 + 0) & 31) * 8 + (((d0 + 0) >> 5) & 1) * 256 + vb] = f2b(v4.x);
        Vt[((d0 + 1) & 31) * 8 + (((d0 + 1) >> 5) & 1) * 256 + vb] = f2b(v4.y);
        Vt[((d0 + 2) & 31) * 8 + (((d0 + 2) >> 5) & 1) * 256 + vb] = f2b(v4.z);
        Vt[((d0 + 3) & 31) * 8 + (((d0 + 3) >> 5) & 1) * 256 + vb] = f2b(v4.w);
    }
    __syncthreads();
    // tile already frag-linear in LDS: plain linear copy-out
    const float4* s = (const float4*)Vt;
    float4* d = (float4*)Vdst;
    d[tid] = s[tid];
    d[tid + 256] = s[tid + 256];
}

// ---------------- pass 2: attention — zero barriers, K/V register-resident ------
// LDS: per-wave slab only (3712 B): wdiag bf16 [32][27] @0, qrel bf16 [32][29] @1792.
// No inter-wave communication of any kind.
__global__ __launch_bounds__(256, 3) void attn_kernel(
        const float* __restrict__ x,
        const float* __restrict__ tk,
        const float* __restrict__ tv,
        const u16t* __restrict__ wsK,
        const u16t* __restrict__ wsV,
        float* __restrict__ out) {
    __shared__ __align__(16) char smem[14848];

    const int tid = threadIdx.x;
    const int work = (blockIdx.x & 7) * (NBLK / 8) + (blockIdx.x >> 3);
    const int qt = work % NQT;
    const int h  = (work / NQT) % Hh;
    const int b  = work / (NQT * Hh);
    const int lane = tid & 63;
    const int w = tid >> 6;
    const int lq = lane & 31;
    const int hi = lane >> 5;
    const int q0 = qt * NQB;
    const int qw0 = q0 + w * 32;

    char* slab   = smem + w * 3712;
    u16t* wdiagw = (u16t*)slab;              // [32][27] bf16
    u16t* qrelw  = (u16t*)(slab + 1792);     // [32][29] bf16

    const u16t* Kbase = wsK + (size_t)((b * Hh + h) * NKT) * TILE_ELEMS;
    const u16t* Vbase = wsV + (size_t)((b * Hh + h) * NKT) * TILE_ELEMS;
    const int lofs = lq * 8 + hi * 512;      // per-lane u16 offset inside a tile

    // ---- tile-0 K/V fragments straight into registers (coalesced dwordx4) ----
    bf16x8 kfr[2][4];   // [kb][slot]
    bf16x8 vfr[4][2];   // [kbj][db]
    {
        const u16t* Kt0 = Kbase + lofs;
        const u16t* Vt0 = Vbase + lofs;
        #pragma unroll
        for (int kb = 0; kb < 2; ++kb)
            #pragma unroll
            for (int slot = 0; slot < 4; ++slot)
                kfr[kb][slot] = *(const bf16x8*)&Kt0[kb * 256 + slot * 1024];
        #pragma unroll
        for (int kbj = 0; kbj < 4; ++kbj)
            #pragma unroll
            for (int db = 0; db < 2; ++db)
                vfr[kbj][db] = *(const bf16x8*)&Vt0[db * 256 + kbj * 1024];
    }

    // ---- Q fragments direct from global, pre-scaled by KK_E ----
    const float* xq = x + (size_t)b * Nn * C3 + (size_t)(qw0 + lq) * C3 + h * 64;
    bf16x8 qB[4];
    #pragma unroll
    for (int slot = 0; slot < 4; ++slot) {
        float4 a4 = *(const float4*)&xq[slot * 16 + hi * 8];
        float4 b4 = *(const float4*)&xq[slot * 16 + hi * 8 + 4];
        union { bf16x8 v; unsigned u[4]; } pk;
        pk.u[0] = pk2a(a4.x * KK_E, a4.y * KK_E);
        pk.u[1] = pk2a(a4.z * KK_E, a4.w * KK_E);
        pk.u[2] = pk2a(b4.x * KK_E, b4.y * KK_E);
        pk.u[3] = pk2a(b4.z * KK_E, b4.w * KK_E);
        qB[slot] = pk.v;
    }

    // ---- qrel[q][t] = (KK_E*Q[q,:]).tk[t,:] via 4 MFMAs: D[q=crow(reg,hi)][t=lq] ----
    {
        const int tc = lq > 28 ? 28 : lq;
        f32x16 qr = {};
        #pragma unroll
        for (int slot = 0; slot < 4; ++slot) {
            const float* tp = &tk[tc * 64 + slot * 16 + hi * 8];
            float4 a4 = *(const float4*)tp;
            float4 b4 = *(const float4*)(tp + 4);
            union { bf16x8 v; unsigned u[4]; } pk;
            pk.u[0] = pk2a(a4.x, a4.y); pk.u[1] = pk2a(a4.z, a4.w);
            pk.u[2] = pk2a(b4.x, b4.y); pk.u[3] = pk2a(b4.z, b4.w);
            qr = __builtin_amdgcn_mfma_f32_32x32x16_bf16(qB[slot], pk.v, qr, 0, 0, 0);
        }
        if (lq <= 28) {
            #pragma unroll
            for (int reg = 0; reg < 16; ++reg) {
                int qrow = (reg & 3) + 8 * (reg >> 2) + 4 * hi;
                qrelw[qrow * NT + lq] = f2b(qr[reg]);
            }
        }
    }
    // zero wdiag (wave-private; compiler orders LDS ops within the wave)
    for (int i = lane; i < 432; i += 64) ((unsigned*)wdiagw)[i] = 0u;

    const float qb0  = b2f(qrelw[lq * NT + 0]);    // already scaled
    const float qb28 = b2f(qrelw[lq * NT + 28]);

    f32x16 of[2] = {};
    float lowA = 0.f, highA = 0.f;

    for (int kt = 0; kt < NKT; ++kt) {
        const int key00 = kt * KVBLK;
        const bool more = (kt + 1 < NKT);
        const u16t* Ktn = Kbase + (size_t)(kt + 1) * TILE_ELEMS + lofs;
        const u16t* Vtn = Vbase + (size_t)(kt + 1) * TILE_ELEMS + lofs;

        #pragma unroll
        for (int kb = 0; kb < 2; ++kb) {
            const int kbase = key00 + kb * 32;
            const bool flo = (kbase + 31 - qw0 <= -14);
            const bool fhi = (kbase - (qw0 + 31) >= 14);
            const float binit = flo ? qb0 : (fhi ? qb28 : 0.f);
            f32x16 s;
            #pragma unroll
            for (int r = 0; r < 16; ++r) s[r] = binit;   // bias folded into C-init
            __builtin_amdgcn_s_setprio(1);
            #pragma unroll
            for (int slot = 0; slot < 4; ++slot)
                s = __builtin_amdgcn_mfma_f32_32x32x16_bf16(kfr[kb][slot], qB[slot], s, 0, 0, 0);
            __builtin_amdgcn_s_setprio(0);
            // phase-shifted reload: K(kt+1) for this kb, right after last use
            if (more) {
                #pragma unroll
                for (int slot = 0; slot < 4; ++slot)
                    kfr[kb][slot] = *(const bf16x8*)&Ktn[kb * 256 + slot * 1024];
            }
            // lane holds S^T[key = kbase+(r&3)+8*(r>>2)+4*hi][q = qw0+lq] (+bias)
            float e[16];
            if (flo || fhi) {
                #pragma unroll
                for (int r = 0; r < 16; ++r) e[r] = exp2f(s[r]);
                float a0 = (e[0]+e[1]) + (e[2]+e[3]);
                float a1 = (e[4]+e[5]) + (e[6]+e[7]);
                float a2 = (e[8]+e[9]) + (e[10]+e[11]);
                float a3 = (e[12]+e[13]) + (e[14]+e[15]);
                float at = (a0+a1) + (a2+a3);
                if (flo) lowA += at; else highA += at;
            } else {
                const int qg = qw0 + lq;
                #pragma unroll
                for (int r = 0; r < 16; ++r) {
                    int key = kbase + (r & 3) + 8 * (r >> 2) + 4 * hi;
                    int delta = key - qg;
                    int t = delta + 14;
                    t = t < 0 ? 0 : (t > 28 ? 28 : t);
                    e[r] = exp2f(s[r] + b2f(qrelw[lq * NT + t]));
                    if (delta <= -14)      lowA += e[r];
                    else if (delta >= 14)  highA += e[r];
                    else                   wdiagw[lq * 27 + delta + 13] = f2b(e[r]);
                }
            }
            // T12: cvt_pk + permlane32_swap -> PV B-frags in registers
            unsigned A0 = pk2a(e[0],  e[1]),  B0 = pk2a(e[2],  e[3]);
            unsigned C0 = pk2a(e[4],  e[5]),  D0 = pk2a(e[6],  e[7]);
            unsigned A1 = pk2a(e[8],  e[9]),  B1 = pk2a(e[10], e[11]);
            unsigned C1 = pk2a(e[12], e[13]), D1 = pk2a(e[14], e[15]);
            v2u r0 = __builtin_amdgcn_permlane32_swap(A0, C0, false, false);
            v2u r1 = __builtin_amdgcn_permlane32_swap(B0, D0, false, false);
            v2u r2 = __builtin_amdgcn_permlane32_swap(A1, C1, false, false);
            v2u r3 = __builtin_amdgcn_permlane32_swap(B1, D1, false, false);
            union { bf16x8 v; unsigned u[4]; } pf0, pf1;
            pf0.u[0] = r0[0]; pf0.u[1] = r1[0]; pf0.u[2] = r0[1]; pf0.u[3] = r1[1];
            pf1.u[0] = r2[0]; pf1.u[1] = r3[0]; pf1.u[2] = r2[1]; pf1.u[3] = r3[1];
            __builtin_amdgcn_s_setprio(1);
            #pragma unroll
            for (int db = 0; db < 2; ++db) {
                of[db] = __builtin_amdgcn_mfma_f32_32x32x16_bf16(vfr[kb*2+0][db], pf0.v, of[db], 0, 0, 0);
                of[db] = __builtin_amdgcn_mfma_f32_32x32x16_bf16(vfr[kb*2+1][db], pf1.v, of[db], 0, 0, 0);
            }
            __builtin_amdgcn_s_setprio(0);
            // phase-shifted reload: V(kt+1) for this kb's two key sub-groups
            if (more) {
                #pragma unroll
                for (int j = 0; j < 2; ++j)
                    #pragma unroll
                    for (int db = 0; db < 2; ++db)
                        vfr[kb*2+j][db] = *(const bf16x8*)&Vtn[db * 256 + (kb*2+j) * 1024];
            }
        }
    }

    // ---- per-lane finish: both hi halves get full row sums via one swap ----
    lowA  += __shfl_xor(lowA, 32, 64);
    highA += __shfl_xor(highA, 32, 64);
    float wsum = lowA + highA;

    // ---- out2 computed directly in the `of` fragment layout (no LDS exchange) ----
    float acc[2][16];
    #pragma unroll
    for (int db = 0; db < 2; ++db)
        #pragma unroll
        for (int rq = 0; rq < 4; ++rq) {
            int d0 = db * 32 + rq * 8 + hi * 4;
            float4 ta = *(const float4*)&tv[d0];
            float4 tb = *(const float4*)&tv[28 * 64 + d0];
            acc[db][rq * 4 + 0] = lowA * ta.x + highA * tb.x;
            acc[db][rq * 4 + 1] = lowA * ta.y + highA * tb.y;
            acc[db][rq * 4 + 2] = lowA * ta.z + highA * tb.z;
            acc[db][rq * 4 + 3] = lowA * ta.w + highA * tb.w;
        }
    for (int t = 1; t <= 27; ++t) {
        float wv = b2f(wdiagw[lq * 27 + t - 1]);
        wsum += wv;
        #pragma unroll
        for (int db = 0; db < 2; ++db)
            #pragma unroll
            for (int rq = 0; rq < 4; ++rq) {
                int d0 = db * 32 + rq * 8 + hi * 4;
                float4 tr = *(const float4*)&tv[t * 64 + d0];
                acc[db][rq * 4 + 0] = fmaf(wv, tr.x, acc[db][rq * 4 + 0]);
                acc[db][rq * 4 + 1] = fmaf(wv, tr.y, acc[db][rq * 4 + 1]);
                acc[db][rq * 4 + 2] = fmaf(wv, tr.z, acc[db][rq * 4 + 2]);
                acc[db][rq * 4 + 3] = fmaf(wv, tr.w, acc[db][rq * 4 + 3]);
            }
    }
    const float linv = 1.f / wsum;

    // ---- epilogue: out[q][d] = (O^T[d][q] + out2[q][d]) / L[q] ----
    {
        float* orow = &out[((size_t)b * Nn + qw0 + lq) * 768 + h * 64];
        #pragma unroll
        for (int db = 0; db < 2; ++db)
            #pragma unroll
            for (int rq = 0; rq < 4; ++rq) {
                int d0 = db * 32 + rq * 8 + hi * 4;
                float4 o4;
                o4.x = (of[db][rq * 4 + 0] + acc[db][rq * 4 + 0]) * linv;
                o4.y = (of[db][rq * 4 + 1] + acc[db][rq * 4 + 1]) * linv;
                o4.z = (of[db][rq * 4 + 2] + acc[db][rq * 4 + 2]) * linv;
                o4.w = (of[db][rq * 4 + 3] + acc[db][rq * 4 + 3]) * linv;
                *(float4*)&orow[d0] = o4;
            }
    }
}

extern "C" void kernel_launch(void* const* d_in, const int* in_sizes, int n_in,
                              void* d_out, int out_size, void* d_ws, size_t ws_size,
                              hipStream_t stream) {
    const float* x  = (const float*)d_in[0];
    const float* tk = (const float*)d_in[1];
    const float* tv = (const float*)d_in[2];
    float* out = (float*)d_out;
    u16t* wsK = (u16t*)d_ws;
    u16t* wsV = wsK + (size_t)Bb * Hh * NKT * TILE_ELEMS;
    preconv_kernel<<<dim3(Bb * Hh * NKT), dim3(256), 0, stream>>>(x, wsK, wsV);
    attn_kernel<<<dim3(NBLK), dim3(256), 0, stream>>>(x, tk, tv, wsK, wsV, out);
}